// Round 7
// baseline (188.062 us; speedup 1.0000x reference)
//
#include <hip/hip_runtime.h>
#include <math.h>

#define N_NODES 10000
#define N_EDGES 50000
#define IN_F    1433
#define OUT_F   256
#define GK      1440          // padded K: multiple of 32, rows 16B-aligned
#define NCHUNK  180           // GK/8
#define GM2     10112         // 79*128: agg rows padded to GEMM M tiles
#define CAP     32            // fixed slots per node; overflow list handles the rest

typedef __bf16 bf16x8 __attribute__((ext_vector_type(8)));
typedef float  f32x4  __attribute__((ext_vector_type(4)));

typedef __attribute__((address_space(3))) unsigned int lds_u32;
typedef __attribute__((address_space(1))) unsigned int glb_u32;

__device__ __forceinline__ void stage16(const void* g, void* l) {
    __builtin_amdgcn_global_load_lds((glb_u32*)g, (lds_u32*)l, 16, 0, 0);
}

// ---------------- phase A: fill + conv + prep in ONE dispatch ----------------
// blocks [0, 196)          : edge binning -- ONE pass, no scan:
//                            pos = atomicAdd(&cnt[dst],1); pos<CAP -> slot,
//                            else overflow list (cnt[N_NODES] = ovf count).
// blocks [196, 2696)       : fp32->bf16 convert of X (4 rows/block)
// blocks [2696, 2786)      : W^T prep -- coalesced f32x4 row reads ->
//                            16 KB LDS tile -> transposed bf16 writes.
//
// conv window-select: wave w owns row r; row start mod 4 == r&3 == d
// (1433 % 4 == 1) -> uniform branch picks dwords [d..d+7] from 3 aligned
// float4 loads, ALL hoisted up front (one latency per row, not three).
// Loads clamp chunk to 178; chunk 178's 12-float window ends at col 1432
// (worst: row 9999, d=3 lands exactly on the last element 14,329,999).
// Chunk 179's single valid float (col 1432) sits at q[8+d] of that window.

#define FILL_BLKS   ((N_EDGES + 255) / 256)   // 196
#define CONV_BLKS   (N_NODES / 4)             // 2500
#define PREP_BLKS   (GK / 16)                 // 90: each block transposes 16 W-rows
#define PHASEA_BLKS (FILL_BLKS + CONV_BLKS + PREP_BLKS)

__global__ void __launch_bounds__(256) k_phaseA(const float* __restrict__ X,
                                                __bf16* __restrict__ Xbf,
                                                const float* __restrict__ W,
                                                __bf16* __restrict__ BT,
                                                const int* __restrict__ edges,
                                                int* __restrict__ cnt,
                                                int* __restrict__ slots,
                                                int* __restrict__ ovf) {
    __shared__ float wt[16][256];             // 16 KB (prep only; not limiting)
    const int t = threadIdx.x;
    const int b = blockIdx.x;

    if (b < FILL_BLKS) {
        // ---- edge binning: hist+fill collapsed into one atomic pass ----
        int e = b * 256 + t;
        if (e < N_EDGES) {
            int dst = edges[2 * e];
            int src = edges[2 * e + 1];
            if ((unsigned)src < N_NODES) {
                int pos = atomicAdd(&cnt[dst], 1);
                if (pos < CAP) {
                    slots[dst * CAP + pos] = src;
                } else {
                    int o = atomicAdd(&cnt[N_NODES], 1);
                    ovf[2 * o]     = dst;
                    ovf[2 * o + 1] = src;
                }
            }
        }
        return;
    }

    if (b < FILL_BLKS + CONV_BLKS) {
        // ---- conv: fp32 -> bf16, ILP-hoisted window-select ----
        const int w = t >> 6, lane = t & 63;
        const int r = (b - FILL_BLKS) * 4 + w;       // 0..9999
        const size_t rowf = (size_t)r * IN_F;
        __bf16* orow = Xbf + (size_t)r * GK;
        const int d = r & 3;

        f32x4 A[3][3];
#pragma unroll
        for (int s2 = 0; s2 < 3; ++s2) {
            int k = lane + s2 * 64;
            int kc = (k > 178) ? 178 : k;            // clamped: always in-bounds
            size_t q0 = (rowf + (size_t)kc * 8) >> 2;
            A[s2][0] = ((const f32x4*)X)[q0];
            A[s2][1] = ((const f32x4*)X)[q0 + 1];
            A[s2][2] = ((const f32x4*)X)[q0 + 2];
        }

#pragma unroll
        for (int s2 = 0; s2 < 3; ++s2) {
            int k = lane + s2 * 64;
            float q[12];
            *(f32x4*)&q[0] = A[s2][0];
            *(f32x4*)&q[4] = A[s2][1];
            *(f32x4*)&q[8] = A[s2][2];
            if (k < 179) {
                bf16x8 v;
                switch (d) {                          // wave-uniform
                case 0:
#pragma unroll
                    for (int j = 0; j < 8; ++j) v[j] = (__bf16)q[0 + j];
                    break;
                case 1:
#pragma unroll
                    for (int j = 0; j < 8; ++j) v[j] = (__bf16)q[1 + j];
                    break;
                case 2:
#pragma unroll
                    for (int j = 0; j < 8; ++j) v[j] = (__bf16)q[2 + j];
                    break;
                default:
#pragma unroll
                    for (int j = 0; j < 8; ++j) v[j] = (__bf16)q[3 + j];
                    break;
                }
                *(bf16x8*)(orow + k * 8) = v;
            } else if (k == 179) {
                bf16x8 v;
                v[0] = (__bf16)q[8 + d];              // float col 1432
#pragma unroll
                for (int j = 1; j < 8; ++j) v[j] = (__bf16)0.0f;
                *(bf16x8*)(orow + 1432) = v;
            }
        }
        return;
    }

    // ---- prep: coalesced W^T via LDS transpose; 16 W-rows per block ----
    {
        const int bp = b - FILL_BLKS - CONV_BLKS;     // 0..89
        const int k0 = bp * 16;
#pragma unroll
        for (int g2 = 0; g2 < 4; ++g2) {
            int g = t + g2 * 256;                     // f32x4 granule 0..1023
            int r = g >> 6, c4 = g & 63;              // row 0..15, col4 0..63
            int krow = k0 + r;
            f32x4 v = (krow < IN_F)
                        ? ((const f32x4*)(W + (size_t)krow * OUT_F))[c4]
                        : (f32x4){0.f, 0.f, 0.f, 0.f};  // zero-pad K 1433..1439
            *(f32x4*)&wt[r][c4 * 4] = v;
        }
        __syncthreads();
        bf16x8 o0, o1;                                // thread t = output col n
#pragma unroll
        for (int r = 0; r < 8; ++r) { o0[r] = (__bf16)wt[r][t]; o1[r] = (__bf16)wt[8 + r][t]; }
        *(bf16x8*)(BT + (size_t)t * GK + k0)     = o0;
        *(bf16x8*)(BT + (size_t)t * GK + k0 + 8) = o1;
    }
}

// ---------------- aggregate: slot-list gathers + fp32 noise init --------------
// agg[i] = noise[i] + sum_{src in N(i)} X[src];  rnorm[i] = 1/max(||agg||,1e-12)
// Neighbor list = slots[node*CAP .. node*CAP+min(cn,CAP)) plus (rare) overflow
// entries with dst==node. Slot reads are wave-uniform -> scalar broadcast.
// noise read DIRECTLY as fp32 with the window-select (d = node&3 block-uniform),
// loads issued before the gather loop so they fly under it.
// grid = GM2: pad rows just write zero (GEMM reads them).

__global__ void __launch_bounds__(192) k_agg(const __bf16* __restrict__ Xbf,
                                             const float* __restrict__ noise,
                                             const int* __restrict__ cnt,
                                             const int* __restrict__ slots,
                                             const int* __restrict__ ovf,
                                             __bf16* __restrict__ aggbf,
                                             float* __restrict__ rnorm) {
    __shared__ float red[3];
    const int node = blockIdx.x;
    const int t = threadIdx.x;
    const bool active = (t < NCHUNK);
    const size_t co = (size_t)t * 8;

    if (node >= N_NODES) {          // pad rows for the GEMM M-tiling
        if (active) {
            bf16x8 z;
#pragma unroll
            for (int j = 0; j < 8; ++j) z[j] = (__bf16)0.0f;
            *(bf16x8*)(aggbf + (size_t)node * GK + co) = z;
        }
        return;
    }

    const size_t nrowf = (size_t)node * IN_F;
    const int d = node & 3;
    f32x4 na, nb, nc;
    if (active) {
        int kc = (t > 178) ? 178 : t;
        size_t q0 = (nrowf + (size_t)kc * 8) >> 2;
        na = ((const f32x4*)noise)[q0];
        nb = ((const f32x4*)noise)[q0 + 1];
        nc = ((const f32x4*)noise)[q0 + 2];
    }

    const int cn = cnt[node];
    const int ns = (cn < CAP) ? cn : CAP;
    const int* sl = slots + node * CAP;

    float acc[8] = {0.f, 0.f, 0.f, 0.f, 0.f, 0.f, 0.f, 0.f};

    int kk = 0;
    for (; kk + 3 < ns; kk += 4) {
        int n0 = sl[kk], n1 = sl[kk + 1];
        int n2 = sl[kk + 2], n3 = sl[kk + 3];
        if (active) {
            bf16x8 v0 = *(const bf16x8*)(Xbf + (size_t)n0 * GK + co);
            bf16x8 v1 = *(const bf16x8*)(Xbf + (size_t)n1 * GK + co);
            bf16x8 v2 = *(const bf16x8*)(Xbf + (size_t)n2 * GK + co);
            bf16x8 v3 = *(const bf16x8*)(Xbf + (size_t)n3 * GK + co);
#pragma unroll
            for (int j = 0; j < 8; ++j)
                acc[j] += ((float)v0[j] + (float)v1[j]) + ((float)v2[j] + (float)v3[j]);
        }
    }
    for (; kk < ns; ++kk) {
        int n0 = sl[kk];
        if (active) {
            bf16x8 v = *(const bf16x8*)(Xbf + (size_t)n0 * GK + co);
#pragma unroll
            for (int j = 0; j < 8; ++j) acc[j] += (float)v[j];
        }
    }

    if (cn > CAP) {                  // exact overflow path (rare/never)
        const int L = cnt[N_NODES];
        for (int i = 0; i < L; ++i) {
            if (ovf[2 * i] == node) {
                int n0 = ovf[2 * i + 1];
                if (active) {
                    bf16x8 v = *(const bf16x8*)(Xbf + (size_t)n0 * GK + co);
#pragma unroll
                    for (int j = 0; j < 8; ++j) acc[j] += (float)v[j];
                }
            }
        }
    }

    // fold fp32 noise via window-select (block-uniform d)
    if (active) {
        float nq[12];
        *(f32x4*)&nq[0] = na; *(f32x4*)&nq[4] = nb; *(f32x4*)&nq[8] = nc;
        if (t < 179) {
            switch (d) {
            case 0:
#pragma unroll
                for (int j = 0; j < 8; ++j) acc[j] += nq[0 + j];
                break;
            case 1:
#pragma unroll
                for (int j = 0; j < 8; ++j) acc[j] += nq[1 + j];
                break;
            case 2:
#pragma unroll
                for (int j = 0; j < 8; ++j) acc[j] += nq[2 + j];
                break;
            default:
#pragma unroll
                for (int j = 0; j < 8; ++j) acc[j] += nq[3 + j];
                break;
            }
        } else {                      // t == 179: only float col 1432 is real
            acc[0] += nq[8 + d];
        }
    }

    float ss = 0.f;
    if (active) {
        bf16x8 o;
#pragma unroll
        for (int j = 0; j < 8; ++j) { o[j] = (__bf16)acc[j]; ss += acc[j] * acc[j]; }
        *(bf16x8*)(aggbf + (size_t)node * GK + co) = o;
    }
    for (int off = 32; off > 0; off >>= 1) ss += __shfl_down(ss, off, 64);
    if ((t & 63) == 0) red[t >> 6] = ss;
    __syncthreads();
    if (t == 0)
        rnorm[node] = 1.0f / fmaxf(sqrtf(red[0] + red[1] + red[2]), 1e-12f);
}

// ---------------- bf16 MFMA GEMM: out = (aggbf @ WbfT^T) * rnorm + bias --------
// v3: BM=64, BN=64, BK=96, 632 blocks; DOUBLE-BUFFERED LDS (2x24 KB) with ONE
// __syncthreads per K-step (15 barriers vs v2's 30): stage(next buf) is issued
// FIRST each iteration, so its HBM latency hides under the 12 ds_reads + 12
// MFMAs before the barrier's vmcnt drain (T3-minimum 2-phase pattern).
// 48 KB LDS -> 3 blocks/CU cap, but grid only needs 632/256 = 2.47 resident.
// Staging coords hoisted to loop-invariant base pointers. Epilogue stores are
// nontemporal (out never re-read; keeps aggbf/BT lines in L2).
// XCD swizzle: 632 = 8*79 exactly -> 4 col-siblings of each 64-row A panel
// land consecutively on one XCD -> A re-reads are L2 hits.

#define BKG 96
#define NKT (GK / BKG)                          // 15
#define GEMM_NWG ((GM2 / 64) * (OUT_F / 64))    // 158*4 = 632

__global__ void __launch_bounds__(256) k_gemm(const __bf16* __restrict__ A,
                                              const __bf16* __restrict__ BT,
                                              const float* __restrict__ rnorm,
                                              const float* __restrict__ bias,
                                              float* __restrict__ out) {
    __shared__ __align__(16) __bf16 Asm[2][64][BKG];   // 2 x 12 KB
    __shared__ __align__(16) __bf16 Bsm[2][64][BKG];   // 2 x 12 KB

    const int t = threadIdx.x;
    const int lane = t & 63;
    const int w = t >> 6;
    const int wr = w >> 1, wc = w & 1;              // 2x2 wave grid

    const int L = blockIdx.x;                        // XCD-bijective swizzle
    const int xcd = L & 7, idx = L >> 3;
    const int work = xcd * (GEMM_NWG / 8) + idx;     // 632 % 8 == 0
    const int row0 = (work >> 2) * 64;
    const int col0 = (work & 3) * 64;

    f32x4 acc[2][2];
#pragma unroll
    for (int i = 0; i < 2; ++i)
#pragma unroll
        for (int j = 0; j < 2; ++j) acc[i][j] = (f32x4){0.f, 0.f, 0.f, 0.f};

    // loop-invariant staging: granule g = t + g2*256 covers (row g/12, 16B-col g%12)
    const __bf16* Ab[3];
    const __bf16* Bb[3];
    int goff[3];
#pragma unroll
    for (int g2 = 0; g2 < 3; ++g2) {
        int g = t + g2 * 256;
        int r = g / 12, c16 = g % 12;
        Ab[g2]   = A  + (size_t)(row0 + r) * GK + c16 * 8;
        Bb[g2]   = BT + (size_t)(col0 + r) * GK + c16 * 8;
        goff[g2] = g * 8;
    }

    auto stage_tile = [&](int buf, int k0) {
#pragma unroll
        for (int g2 = 0; g2 < 3; ++g2) {
            stage16(Ab[g2] + k0, (__bf16*)Asm[buf] + goff[g2]);
            stage16(Bb[g2] + k0, (__bf16*)Bsm[buf] + goff[g2]);
        }
    };

    stage_tile(0, 0);

    const int kq = (lane >> 4) * 8;
    const int l15 = lane & 15;

    __syncthreads();                                 // drains prologue stage

    for (int kt = 0; kt < NKT; ++kt) {
        const int cur = kt & 1;
        if (kt + 1 < NKT) stage_tile(cur ^ 1, (kt + 1) * BKG);   // issue EARLY

        bf16x8 af[2][3], bfr[2][3];
#pragma unroll
        for (int s = 0; s < 3; ++s) {
#pragma unroll
            for (int i = 0; i < 2; ++i) {
                af[i][s]  = *(const bf16x8*)&Asm[cur][wr * 32 + i * 16 + l15][s * 32 + kq];
                bfr[i][s] = *(const bf16x8*)&Bsm[cur][wc * 32 + i * 16 + l15][s * 32 + kq];
            }
        }

#pragma unroll
        for (int s = 0; s < 3; ++s)
#pragma unroll
            for (int i = 0; i < 2; ++i)
#pragma unroll
                for (int j = 0; j < 2; ++j)
                    acc[i][j] = __builtin_amdgcn_mfma_f32_16x16x32_bf16(af[i][s], bfr[j][s], acc[i][j], 0, 0, 0);

        __syncthreads();     // ONE barrier/iter: drains stage (vmcnt) + read hazard
    }

    // epilogue: C/D layout col=lane&15, row=(lane>>4)*4+reg; fuse rnorm + bias
    const int rq4 = (lane >> 4) * 4;
#pragma unroll
    for (int i = 0; i < 2; ++i) {
        int gr0 = row0 + wr * 32 + i * 16 + rq4;
#pragma unroll
        for (int rr = 0; rr < 4; ++rr) {
            int gr = gr0 + rr;
            if (gr < N_NODES) {
                float rn = rnorm[gr];
#pragma unroll
                for (int j = 0; j < 2; ++j) {
                    int gc = col0 + wc * 32 + j * 16 + l15;
                    __builtin_nontemporal_store(acc[i][j][rr] * rn + bias[gc],
                                                &out[(size_t)gr * OUT_F + gc]);
                }
            }
        }
    }
}

// ---------------- launch ----------------

extern "C" void kernel_launch(void* const* d_in, const int* in_sizes, int n_in,
                              void* d_out, int out_size, void* d_ws, size_t ws_size,
                              hipStream_t stream) {
    const float* feat  = (const float*)d_in[0];
    const int*   edges = (const int*)d_in[1];
    const float* W     = (const float*)d_in[2];
    const float* bias  = (const float*)d_in[3];
    const float* noise = (const float*)d_in[4];
    float* out = (float*)d_out;

    char* ws = (char*)d_ws;
    size_t off = 0;
    auto carve = [&](size_t bytes) {
        void* p = ws + off;
        off = (off + bytes + 255) & ~(size_t)255;
        return p;
    };
    __bf16* Xbf     = (__bf16*)carve((size_t)N_NODES * GK * sizeof(__bf16));
    __bf16* aggbf   = (__bf16*)carve((size_t)GM2 * GK * sizeof(__bf16));
    __bf16* WbfT    = (__bf16*)carve((size_t)OUT_F * GK * sizeof(__bf16));
    float*  rnorm   = (float*)carve((size_t)N_NODES * sizeof(float));
    int*    cnt     = (int*)carve((size_t)(N_NODES + 1) * sizeof(int));   // +ovf count
    int*    slots   = (int*)carve((size_t)N_NODES * CAP * sizeof(int));
    int*    ovf     = (int*)carve((size_t)2 * N_EDGES * sizeof(int));
    (void)ws_size;

    hipMemsetAsync(cnt, 0, (size_t)(N_NODES + 1) * sizeof(int), stream);

    k_phaseA<<<PHASEA_BLKS, 256, 0, stream>>>(feat, Xbf, W, WbfT,
                                              edges, cnt, slots, ovf);

    k_agg<<<GM2, 192, 0, stream>>>(Xbf, noise, cnt, slots, ovf, aggbf, rnorm);

    k_gemm<<<GEMM_NWG, 256, 0, stream>>>(aggbf, WbfT, rnorm, bias, out);
}

// Round 8
// 186.785 us; speedup vs baseline: 1.0068x; 1.0068x over previous
//
#include <hip/hip_runtime.h>
#include <math.h>

#define N_NODES 10000
#define N_EDGES 50000
#define IN_F    1433
#define OUT_F   256
#define GK      1440          // padded K: multiple of 32, rows 16B-aligned
#define NCHUNK  180           // GK/8
#define GM2     10112         // 79*128: agg rows padded to GEMM M tiles
#define CAP     32            // fixed slots per node; overflow list handles the rest

typedef __bf16 bf16x8 __attribute__((ext_vector_type(8)));
typedef float  f32x4  __attribute__((ext_vector_type(4)));

typedef __attribute__((address_space(3))) unsigned int lds_u32;
typedef __attribute__((address_space(1))) unsigned int glb_u32;

__device__ __forceinline__ void stage16(const void* g, void* l) {
    __builtin_amdgcn_global_load_lds((glb_u32*)g, (lds_u32*)l, 16, 0, 0);
}

// ---------------- phase A: fill + conv + prep in ONE dispatch ----------------
// blocks [0, 196)          : edge binning -- ONE pass, no scan:
//                            pos = atomicAdd(&cnt[dst],1); pos<CAP -> slot,
//                            else overflow list (cnt[N_NODES] = ovf count).
// blocks [196, 2696)       : fp32->bf16 convert of X (4 rows/block)
// blocks [2696, 2786)      : W^T prep -- coalesced f32x4 row reads ->
//                            16 KB LDS tile -> transposed bf16 writes.
//
// conv window-select: wave w owns row r; row start mod 4 == r&3 == d
// (1433 % 4 == 1) -> uniform branch picks dwords [d..d+7] from 3 aligned
// float4 loads, ALL hoisted up front (one latency per row, not three).
// Loads clamp chunk to 178; chunk 178's 12-float window ends at col 1432
// (worst: row 9999, d=3 lands exactly on the last element 14,329,999).
// Chunk 179's single valid float (col 1432) sits at q[8+d] of that window.

#define FILL_BLKS   ((N_EDGES + 255) / 256)   // 196
#define CONV_BLKS   (N_NODES / 4)             // 2500
#define PREP_BLKS   (GK / 16)                 // 90: each block transposes 16 W-rows
#define PHASEA_BLKS (FILL_BLKS + CONV_BLKS + PREP_BLKS)

__global__ void __launch_bounds__(256) k_phaseA(const float* __restrict__ X,
                                                __bf16* __restrict__ Xbf,
                                                const float* __restrict__ W,
                                                __bf16* __restrict__ BT,
                                                const int* __restrict__ edges,
                                                int* __restrict__ cnt,
                                                int* __restrict__ slots,
                                                int* __restrict__ ovf) {
    __shared__ float wt[16][256];             // 16 KB (prep only; not limiting)
    const int t = threadIdx.x;
    const int b = blockIdx.x;

    if (b < FILL_BLKS) {
        // ---- edge binning: hist+fill collapsed into one atomic pass ----
        int e = b * 256 + t;
        if (e < N_EDGES) {
            int dst = edges[2 * e];
            int src = edges[2 * e + 1];
            if ((unsigned)src < N_NODES) {
                int pos = atomicAdd(&cnt[dst], 1);
                if (pos < CAP) {
                    slots[dst * CAP + pos] = src;
                } else {
                    int o = atomicAdd(&cnt[N_NODES], 1);
                    ovf[2 * o]     = dst;
                    ovf[2 * o + 1] = src;
                }
            }
        }
        return;
    }

    if (b < FILL_BLKS + CONV_BLKS) {
        // ---- conv: fp32 -> bf16, ILP-hoisted window-select ----
        const int w = t >> 6, lane = t & 63;
        const int r = (b - FILL_BLKS) * 4 + w;       // 0..9999
        const size_t rowf = (size_t)r * IN_F;
        __bf16* orow = Xbf + (size_t)r * GK;
        const int d = r & 3;

        f32x4 A[3][3];
#pragma unroll
        for (int s2 = 0; s2 < 3; ++s2) {
            int k = lane + s2 * 64;
            int kc = (k > 178) ? 178 : k;            // clamped: always in-bounds
            size_t q0 = (rowf + (size_t)kc * 8) >> 2;
            A[s2][0] = ((const f32x4*)X)[q0];
            A[s2][1] = ((const f32x4*)X)[q0 + 1];
            A[s2][2] = ((const f32x4*)X)[q0 + 2];
        }

#pragma unroll
        for (int s2 = 0; s2 < 3; ++s2) {
            int k = lane + s2 * 64;
            float q[12];
            *(f32x4*)&q[0] = A[s2][0];
            *(f32x4*)&q[4] = A[s2][1];
            *(f32x4*)&q[8] = A[s2][2];
            if (k < 179) {
                bf16x8 v;
                switch (d) {                          // wave-uniform
                case 0:
#pragma unroll
                    for (int j = 0; j < 8; ++j) v[j] = (__bf16)q[0 + j];
                    break;
                case 1:
#pragma unroll
                    for (int j = 0; j < 8; ++j) v[j] = (__bf16)q[1 + j];
                    break;
                case 2:
#pragma unroll
                    for (int j = 0; j < 8; ++j) v[j] = (__bf16)q[2 + j];
                    break;
                default:
#pragma unroll
                    for (int j = 0; j < 8; ++j) v[j] = (__bf16)q[3 + j];
                    break;
                }
                *(bf16x8*)(orow + k * 8) = v;
            } else if (k == 179) {
                bf16x8 v;
                v[0] = (__bf16)q[8 + d];              // float col 1432
#pragma unroll
                for (int j = 1; j < 8; ++j) v[j] = (__bf16)0.0f;
                *(bf16x8*)(orow + 1432) = v;
            }
        }
        return;
    }

    // ---- prep: coalesced W^T via LDS transpose; 16 W-rows per block ----
    {
        const int bp = b - FILL_BLKS - CONV_BLKS;     // 0..89
        const int k0 = bp * 16;
#pragma unroll
        for (int g2 = 0; g2 < 4; ++g2) {
            int g = t + g2 * 256;                     // f32x4 granule 0..1023
            int r = g >> 6, c4 = g & 63;              // row 0..15, col4 0..63
            int krow = k0 + r;
            f32x4 v = (krow < IN_F)
                        ? ((const f32x4*)(W + (size_t)krow * OUT_F))[c4]
                        : (f32x4){0.f, 0.f, 0.f, 0.f};  // zero-pad K 1433..1439
            *(f32x4*)&wt[r][c4 * 4] = v;
        }
        __syncthreads();
        bf16x8 o0, o1;                                // thread t = output col n
#pragma unroll
        for (int r = 0; r < 8; ++r) { o0[r] = (__bf16)wt[r][t]; o1[r] = (__bf16)wt[8 + r][t]; }
        *(bf16x8*)(BT + (size_t)t * GK + k0)     = o0;
        *(bf16x8*)(BT + (size_t)t * GK + k0 + 8) = o1;
    }
}

// ---------------- aggregate v2: TWO nodes per block (2x memory parallelism) ---
// Round-7 PMC: k_agg 41.9us, VGPR=32, VALUBusy 15.7%, HBM 38% -> latency-bound
// with only ~4 row-loads in flight per block. v2: each block owns nodes
// {2b, 2b+1}; the two gather chains are independent, so all 8 row-loads issue
// before either accumulation waits (2x MLP/wave). Noise loads moved AFTER the
// gather loop (needed only at fold; cross-block TLP hides their latency) to
// keep peak live VGPRs <= ~64 and preserve the 32-wave/CU occupancy cap.
// N_NODES even -> every block is fully-real or fully-pad (no straddle).

#define AGG_BLKS (GM2 / 2)    // 5056

__global__ void __launch_bounds__(192) k_agg(const __bf16* __restrict__ Xbf,
                                             const float* __restrict__ noise,
                                             const int* __restrict__ cnt,
                                             const int* __restrict__ slots,
                                             const int* __restrict__ ovf,
                                             __bf16* __restrict__ aggbf,
                                             float* __restrict__ rnorm) {
    __shared__ float red[2][3];
    const int t = threadIdx.x;
    const bool active = (t < NCHUNK);
    const size_t co = (size_t)t * 8;
    const int base = blockIdx.x * 2;

    if (base >= N_NODES) {          // pad rows for the GEMM M-tiling
        if (active) {
            bf16x8 z;
#pragma unroll
            for (int j = 0; j < 8; ++j) z[j] = (__bf16)0.0f;
            *(bf16x8*)(aggbf + (size_t)base * GK + co)       = z;
            *(bf16x8*)(aggbf + (size_t)(base + 1) * GK + co) = z;
        }
        return;
    }

    const int cn0 = cnt[base],     ns0 = (cn0 < CAP) ? cn0 : CAP;
    const int cn1 = cnt[base + 1], ns1 = (cn1 < CAP) ? cn1 : CAP;
    const int* sl0 = slots + base * CAP;
    const int* sl1 = slots + (base + 1) * CAP;

    float acc0[8] = {0.f, 0.f, 0.f, 0.f, 0.f, 0.f, 0.f, 0.f};
    float acc1[8] = {0.f, 0.f, 0.f, 0.f, 0.f, 0.f, 0.f, 0.f};

    const int mx = (ns0 > ns1) ? ns0 : ns1;
    for (int kk = 0; kk < mx; kk += 4) {
        const int ca = ns0 - kk, cb = ns1 - kk;      // block-uniform counts
        bf16x8 va[4], vb[4];
        if (active) {
            // issue ALL loads (both nodes) before any accumulation waits
#pragma unroll
            for (int j = 0; j < 4; ++j)
                if (j < ca) va[j] = *(const bf16x8*)(Xbf + (size_t)sl0[kk + j] * GK + co);
#pragma unroll
            for (int j = 0; j < 4; ++j)
                if (j < cb) vb[j] = *(const bf16x8*)(Xbf + (size_t)sl1[kk + j] * GK + co);
#pragma unroll
            for (int j = 0; j < 4; ++j)
                if (j < ca)
#pragma unroll
                    for (int jj = 0; jj < 8; ++jj) acc0[jj] += (float)va[j][jj];
#pragma unroll
            for (int j = 0; j < 4; ++j)
                if (j < cb)
#pragma unroll
                    for (int jj = 0; jj < 8; ++jj) acc1[jj] += (float)vb[j][jj];
        }
    }

    if (cn0 > CAP || cn1 > CAP) {    // exact overflow path (rare/never)
        const int L = cnt[N_NODES];
        for (int i = 0; i < L; ++i) {
            int dv = ovf[2 * i];
            if (dv == base || dv == base + 1) {
                int n0 = ovf[2 * i + 1];
                if (active) {
                    bf16x8 v = *(const bf16x8*)(Xbf + (size_t)n0 * GK + co);
                    float* ac = (dv == base) ? acc0 : acc1;
#pragma unroll
                    for (int j = 0; j < 8; ++j) ac[j] += (float)v[j];
                }
            }
        }
    }

    // fp32 noise: loaded here (post-gather) to cap live registers; folded via
    // window-select (d block-uniform per node; see k_phaseA conv comment)
    float ss0 = 0.f, ss1 = 0.f;
    if (active) {
        const int kc = (t > 178) ? 178 : t;
#pragma unroll
        for (int p = 0; p < 2; ++p) {
            const int node = base + p;
            const int d = node & 3;
            size_t q0 = ((size_t)node * IN_F + (size_t)kc * 8) >> 2;
            f32x4 na = ((const f32x4*)noise)[q0];
            f32x4 nb = ((const f32x4*)noise)[q0 + 1];
            f32x4 nc = ((const f32x4*)noise)[q0 + 2];
            float nq[12];
            *(f32x4*)&nq[0] = na; *(f32x4*)&nq[4] = nb; *(f32x4*)&nq[8] = nc;
            float* ac = p ? acc1 : acc0;
            if (t < 179) {
                switch (d) {
                case 0:
#pragma unroll
                    for (int j = 0; j < 8; ++j) ac[j] += nq[0 + j];
                    break;
                case 1:
#pragma unroll
                    for (int j = 0; j < 8; ++j) ac[j] += nq[1 + j];
                    break;
                case 2:
#pragma unroll
                    for (int j = 0; j < 8; ++j) ac[j] += nq[2 + j];
                    break;
                default:
#pragma unroll
                    for (int j = 0; j < 8; ++j) ac[j] += nq[3 + j];
                    break;
                }
            } else {                  // t == 179: only float col 1432 is real
                ac[0] += nq[8 + d];
            }
            bf16x8 o;
            float ss = 0.f;
#pragma unroll
            for (int j = 0; j < 8; ++j) { o[j] = (__bf16)ac[j]; ss += ac[j] * ac[j]; }
            *(bf16x8*)(aggbf + (size_t)node * GK + co) = o;
            if (p) ss1 = ss; else ss0 = ss;
        }
    }

    for (int off = 32; off > 0; off >>= 1) {
        ss0 += __shfl_down(ss0, off, 64);
        ss1 += __shfl_down(ss1, off, 64);
    }
    if ((t & 63) == 0) { red[0][t >> 6] = ss0; red[1][t >> 6] = ss1; }
    __syncthreads();
    if (t < 2)
        rnorm[base + t] = 1.0f / fmaxf(sqrtf(red[t][0] + red[t][1] + red[t][2]), 1e-12f);
}

// ---------------- bf16 MFMA GEMM: out = (aggbf @ WbfT^T) * rnorm + bias --------
// v2 (round-6 verbatim; v3 dbuf regressed +4us, reverted): BM=64, BN=64, BK=96
// -> 632 blocks (2.47/CU), 15 K-iterations. 4 waves in a 2x2 grid, each 32x32.
// XCD swizzle: 632 = 8*79 exactly -> the 4 col-siblings sharing a 64-row A
// panel land consecutively on one XCD -> A re-reads are L2 hits.

#define BKG 96
#define GEMM_NWG ((GM2 / 64) * (OUT_F / 64))   // 158*4 = 632

__global__ void __launch_bounds__(256) k_gemm(const __bf16* __restrict__ A,
                                              const __bf16* __restrict__ BT,
                                              const float* __restrict__ rnorm,
                                              const float* __restrict__ bias,
                                              float* __restrict__ out) {
    __shared__ __align__(16) __bf16 Asm[64][BKG];   // 12 KB
    __shared__ __align__(16) __bf16 Bsm[64][BKG];   // 12 KB

    const int t = threadIdx.x;
    const int lane = t & 63;
    const int w = t >> 6;
    const int wr = w >> 1, wc = w & 1;              // 2x2 wave grid

    const int L = blockIdx.x;                        // XCD-bijective swizzle
    const int xcd = L & 7, idx = L >> 3;
    const int work = xcd * (GEMM_NWG / 8) + idx;     // 632 % 8 == 0
    const int row0 = (work >> 2) * 64;
    const int col0 = (work & 3) * 64;

    f32x4 acc[2][2];
#pragma unroll
    for (int i = 0; i < 2; ++i)
#pragma unroll
        for (int j = 0; j < 2; ++j) acc[i][j] = (f32x4){0.f, 0.f, 0.f, 0.f};

    __bf16* asm0 = (__bf16*)Asm;
    __bf16* bsm0 = (__bf16*)Bsm;

    // staging: 64 rows x 12 granules(16B) = 768 granules each side; 3/thread
    auto stage_tile = [&](int k0) {
#pragma unroll
        for (int g2 = 0; g2 < 3; ++g2) {
            int g = t + g2 * 256;
            int r = g / 12, c16 = g % 12;
            stage16(A  + (size_t)(row0 + r) * GK + k0 + c16 * 8, asm0 + g * 8);
            stage16(BT + (size_t)(col0 + r) * GK + k0 + c16 * 8, bsm0 + g * 8);
        }
    };

    stage_tile(0);

    const int kq = (lane >> 4) * 8;
    const int l15 = lane & 15;

    for (int kt = 0; kt < GK / BKG; ++kt) {
        __syncthreads();

        bf16x8 af[2][3], bfr[2][3];
#pragma unroll
        for (int s = 0; s < 3; ++s) {
#pragma unroll
            for (int i = 0; i < 2; ++i) {
                af[i][s]  = *(const bf16x8*)&Asm[wr * 32 + i * 16 + l15][s * 32 + kq];
                bfr[i][s] = *(const bf16x8*)&Bsm[wc * 32 + i * 16 + l15][s * 32 + kq];
            }
        }

        __syncthreads();

        if (kt + 1 < GK / BKG) stage_tile((kt + 1) * BKG);

#pragma unroll
        for (int s = 0; s < 3; ++s)
#pragma unroll
            for (int i = 0; i < 2; ++i)
#pragma unroll
                for (int j = 0; j < 2; ++j)
                    acc[i][j] = __builtin_amdgcn_mfma_f32_16x16x32_bf16(af[i][s], bfr[j][s], acc[i][j], 0, 0, 0);
    }

    // epilogue: C/D layout col=lane&15, row=(lane>>4)*4+reg; fuse rnorm + bias
    const int rq4 = (lane >> 4) * 4;
#pragma unroll
    for (int i = 0; i < 2; ++i) {
        int gr0 = row0 + wr * 32 + i * 16 + rq4;
#pragma unroll
        for (int rr = 0; rr < 4; ++rr) {
            int gr = gr0 + rr;
            if (gr < N_NODES) {
                float rn = rnorm[gr];
#pragma unroll
                for (int j = 0; j < 2; ++j) {
                    int gc = col0 + wc * 32 + j * 16 + l15;
                    out[(size_t)gr * OUT_F + gc] = acc[i][j][rr] * rn + bias[gc];
                }
            }
        }
    }
}

// ---------------- launch ----------------

extern "C" void kernel_launch(void* const* d_in, const int* in_sizes, int n_in,
                              void* d_out, int out_size, void* d_ws, size_t ws_size,
                              hipStream_t stream) {
    const float* feat  = (const float*)d_in[0];
    const int*   edges = (const int*)d_in[1];
    const float* W     = (const float*)d_in[2];
    const float* bias  = (const float*)d_in[3];
    const float* noise = (const float*)d_in[4];
    float* out = (float*)d_out;

    char* ws = (char*)d_ws;
    size_t off = 0;
    auto carve = [&](size_t bytes) {
        void* p = ws + off;
        off = (off + bytes + 255) & ~(size_t)255;
        return p;
    };
    __bf16* Xbf     = (__bf16*)carve((size_t)N_NODES * GK * sizeof(__bf16));
    __bf16* aggbf   = (__bf16*)carve((size_t)GM2 * GK * sizeof(__bf16));
    __bf16* WbfT    = (__bf16*)carve((size_t)OUT_F * GK * sizeof(__bf16));
    float*  rnorm   = (float*)carve((size_t)N_NODES * sizeof(float));
    int*    cnt     = (int*)carve((size_t)(N_NODES + 1) * sizeof(int));   // +ovf count
    int*    slots   = (int*)carve((size_t)N_NODES * CAP * sizeof(int));
    int*    ovf     = (int*)carve((size_t)2 * N_EDGES * sizeof(int));
    (void)ws_size;

    hipMemsetAsync(cnt, 0, (size_t)(N_NODES + 1) * sizeof(int), stream);

    k_phaseA<<<PHASEA_BLKS, 256, 0, stream>>>(feat, Xbf, W, WbfT,
                                              edges, cnt, slots, ovf);

    k_agg<<<AGG_BLKS, 192, 0, stream>>>(Xbf, noise, cnt, slots, ovf, aggbf, rnorm);

    k_gemm<<<GEMM_NWG, 256, 0, stream>>>(aggbf, WbfT, rnorm, bias, out);
}

// Round 9
// 184.057 us; speedup vs baseline: 1.0218x; 1.0148x over previous
//
#include <hip/hip_runtime.h>
#include <math.h>

#define N_NODES 10000
#define N_EDGES 50000
#define IN_F    1433
#define OUT_F   256
#define GK      1440          // padded K: multiple of 32, rows 16B-aligned
#define NCHUNK  180           // GK/8
#define GM2     10112         // 79*128: agg rows padded to GEMM M tiles
#define CAP     32            // fixed slots per node; overflow list handles the rest

typedef __bf16 bf16x8 __attribute__((ext_vector_type(8)));
typedef float  f32x4  __attribute__((ext_vector_type(4)));

typedef __attribute__((address_space(3))) unsigned int lds_u32;
typedef __attribute__((address_space(1))) unsigned int glb_u32;

__device__ __forceinline__ void stage16(const void* g, void* l) {
    __builtin_amdgcn_global_load_lds((glb_u32*)g, (lds_u32*)l, 16, 0, 0);
}

// ---------------- phase A: fill + conv + prep in ONE dispatch ----------------
// blocks [0, 196)          : edge binning -- ONE pass, no scan:
//                            pos = atomicAdd(&cnt[dst],1); pos<CAP -> slot,
//                            else overflow list (cnt[N_NODES] = ovf count).
// blocks [196, 2696)       : fp32->bf16 convert of X (4 rows/block)
// blocks [2696, 2786)      : W^T prep -- coalesced f32x4 row reads ->
//                            16 KB LDS tile -> transposed bf16 writes.
//
// conv window-select: wave w owns row r; row start mod 4 == r&3 == d
// (1433 % 4 == 1) -> uniform branch picks dwords [d..d+7] from 3 aligned
// float4 loads, ALL hoisted up front (one latency per row, not three).
// Loads clamp chunk to 178; chunk 178's 12-float window ends at col 1432
// (worst: row 9999, d=3 lands exactly on the last element 14,329,999).
// Chunk 179's single valid float (col 1432) sits at q[8+d] of that window.

#define FILL_BLKS   ((N_EDGES + 255) / 256)   // 196
#define CONV_BLKS   (N_NODES / 4)             // 2500
#define PREP_BLKS   (GK / 16)                 // 90: each block transposes 16 W-rows
#define PHASEA_BLKS (FILL_BLKS + CONV_BLKS + PREP_BLKS)

__global__ void __launch_bounds__(256) k_phaseA(const float* __restrict__ X,
                                                __bf16* __restrict__ Xbf,
                                                const float* __restrict__ W,
                                                __bf16* __restrict__ BT,
                                                const int* __restrict__ edges,
                                                int* __restrict__ cnt,
                                                int* __restrict__ slots,
                                                int* __restrict__ ovf) {
    __shared__ float wt[16][256];             // 16 KB (prep only; not limiting)
    const int t = threadIdx.x;
    const int b = blockIdx.x;

    if (b < FILL_BLKS) {
        // ---- edge binning: hist+fill collapsed into one atomic pass ----
        int e = b * 256 + t;
        if (e < N_EDGES) {
            int dst = edges[2 * e];
            int src = edges[2 * e + 1];
            if ((unsigned)src < N_NODES) {
                int pos = atomicAdd(&cnt[dst], 1);
                if (pos < CAP) {
                    slots[dst * CAP + pos] = src;
                } else {
                    int o = atomicAdd(&cnt[N_NODES], 1);
                    ovf[2 * o]     = dst;
                    ovf[2 * o + 1] = src;
                }
            }
        }
        return;
    }

    if (b < FILL_BLKS + CONV_BLKS) {
        // ---- conv: fp32 -> bf16, ILP-hoisted window-select ----
        const int w = t >> 6, lane = t & 63;
        const int r = (b - FILL_BLKS) * 4 + w;       // 0..9999
        const size_t rowf = (size_t)r * IN_F;
        __bf16* orow = Xbf + (size_t)r * GK;
        const int d = r & 3;

        f32x4 A[3][3];
#pragma unroll
        for (int s2 = 0; s2 < 3; ++s2) {
            int k = lane + s2 * 64;
            int kc = (k > 178) ? 178 : k;            // clamped: always in-bounds
            size_t q0 = (rowf + (size_t)kc * 8) >> 2;
            A[s2][0] = ((const f32x4*)X)[q0];
            A[s2][1] = ((const f32x4*)X)[q0 + 1];
            A[s2][2] = ((const f32x4*)X)[q0 + 2];
        }

#pragma unroll
        for (int s2 = 0; s2 < 3; ++s2) {
            int k = lane + s2 * 64;
            float q[12];
            *(f32x4*)&q[0] = A[s2][0];
            *(f32x4*)&q[4] = A[s2][1];
            *(f32x4*)&q[8] = A[s2][2];
            if (k < 179) {
                bf16x8 v;
                switch (d) {                          // wave-uniform
                case 0:
#pragma unroll
                    for (int j = 0; j < 8; ++j) v[j] = (__bf16)q[0 + j];
                    break;
                case 1:
#pragma unroll
                    for (int j = 0; j < 8; ++j) v[j] = (__bf16)q[1 + j];
                    break;
                case 2:
#pragma unroll
                    for (int j = 0; j < 8; ++j) v[j] = (__bf16)q[2 + j];
                    break;
                default:
#pragma unroll
                    for (int j = 0; j < 8; ++j) v[j] = (__bf16)q[3 + j];
                    break;
                }
                *(bf16x8*)(orow + k * 8) = v;
            } else if (k == 179) {
                bf16x8 v;
                v[0] = (__bf16)q[8 + d];              // float col 1432
#pragma unroll
                for (int j = 1; j < 8; ++j) v[j] = (__bf16)0.0f;
                *(bf16x8*)(orow + 1432) = v;
            }
        }
        return;
    }

    // ---- prep: coalesced W^T via LDS transpose; 16 W-rows per block ----
    {
        const int bp = b - FILL_BLKS - CONV_BLKS;     // 0..89
        const int k0 = bp * 16;
#pragma unroll
        for (int g2 = 0; g2 < 4; ++g2) {
            int g = t + g2 * 256;                     // f32x4 granule 0..1023
            int r = g >> 6, c4 = g & 63;              // row 0..15, col4 0..63
            int krow = k0 + r;
            f32x4 v = (krow < IN_F)
                        ? ((const f32x4*)(W + (size_t)krow * OUT_F))[c4]
                        : (f32x4){0.f, 0.f, 0.f, 0.f};  // zero-pad K 1433..1439
            *(f32x4*)&wt[r][c4 * 4] = v;
        }
        __syncthreads();
        bf16x8 o0, o1;                                // thread t = output col n
#pragma unroll
        for (int r = 0; r < 8; ++r) { o0[r] = (__bf16)wt[r][t]; o1[r] = (__bf16)wt[8 + r][t]; }
        *(bf16x8*)(BT + (size_t)t * GK + k0)     = o0;
        *(bf16x8*)(BT + (size_t)t * GK + k0 + 8) = o1;
    }
}

// ---------------- aggregate v3: branch-free 6-wide gather cluster -------------
// Round-8 lesson: predicated loads (if j<ca inside the body) destroy the load
// cluster -- per-wave MLP comes from BRANCH-FREE load runs. v3 = v1 skeleton
// (1 node/block, 10112 blocks, noise issued early) + shortened serial chain:
//   cnt[node] and the FIRST 6 slot indices (two wave-uniform int4 loads off the
//   128 B contiguous slot row) issue concurrently; then up to 6 row-loads go
//   out in ONE straight-line cluster via a uniform fallthrough switch (named
//   registers, static indices -> no scratch). 76% of nodes (Poisson lam=5,
//   deg<=6) finish the gather in a single memory-latency round. deg>6
//   continues with the clean 4-wide loop from kk=6.

__global__ void __launch_bounds__(192) k_agg(const __bf16* __restrict__ Xbf,
                                             const float* __restrict__ noise,
                                             const int* __restrict__ cnt,
                                             const int* __restrict__ slots,
                                             const int* __restrict__ ovf,
                                             __bf16* __restrict__ aggbf,
                                             float* __restrict__ rnorm) {
    __shared__ float red[3];
    const int node = blockIdx.x;
    const int t = threadIdx.x;
    const bool active = (t < NCHUNK);
    const size_t co = (size_t)t * 8;

    if (node >= N_NODES) {          // pad rows for the GEMM M-tiling
        if (active) {
            bf16x8 z;
#pragma unroll
            for (int j = 0; j < 8; ++j) z[j] = (__bf16)0.0f;
            *(bf16x8*)(aggbf + (size_t)node * GK + co) = z;
        }
        return;
    }

    // early: noise window loads (fp32; clamped chunk <= 178 in-bounds, see
    // k_phaseA conv comment) -- in flight across the whole gather
    const size_t nrowf = (size_t)node * IN_F;
    const int d = node & 3;
    f32x4 na, nb, nc;
    if (active) {
        int kc = (t > 178) ? 178 : t;
        size_t q0 = (nrowf + (size_t)kc * 8) >> 2;
        na = ((const f32x4*)noise)[q0];
        nb = ((const f32x4*)noise)[q0 + 1];
        nc = ((const f32x4*)noise)[q0 + 2];
    }

    // early: degree + first 6 slot indices (concurrent, wave-uniform)
    const int cn = cnt[node];
    const int* sl = slots + node * CAP;               // 128 B row, 16B-aligned
    const int4 w0 = ((const int4*)sl)[0];             // idx 0..3
    const int4 w1 = ((const int4*)sl)[1];             // idx 4..7 (4,5 used)
    const int ns = (cn < CAP) ? cn : CAP;
    const int c6 = (ns < 6) ? ns : 6;

    float acc[8] = {0.f, 0.f, 0.f, 0.f, 0.f, 0.f, 0.f, 0.f};

    bf16x8 v0_, v1_, v2_, v3_, v4_, v5_;              // named: static indexing
    if (active) {
        switch (c6) {                                  // uniform; straight-line loads
        case 6: v5_ = *(const bf16x8*)(Xbf + (size_t)w1.y * GK + co); [[fallthrough]];
        case 5: v4_ = *(const bf16x8*)(Xbf + (size_t)w1.x * GK + co); [[fallthrough]];
        case 4: v3_ = *(const bf16x8*)(Xbf + (size_t)w0.w * GK + co); [[fallthrough]];
        case 3: v2_ = *(const bf16x8*)(Xbf + (size_t)w0.z * GK + co); [[fallthrough]];
        case 2: v1_ = *(const bf16x8*)(Xbf + (size_t)w0.y * GK + co); [[fallthrough]];
        case 1: v0_ = *(const bf16x8*)(Xbf + (size_t)w0.x * GK + co); [[fallthrough]];
        default: break;
        }
        switch (c6) {
        case 6:
#pragma unroll
            for (int j = 0; j < 8; ++j) acc[j] += (float)v5_[j]; [[fallthrough]];
        case 5:
#pragma unroll
            for (int j = 0; j < 8; ++j) acc[j] += (float)v4_[j]; [[fallthrough]];
        case 4:
#pragma unroll
            for (int j = 0; j < 8; ++j) acc[j] += (float)v3_[j]; [[fallthrough]];
        case 3:
#pragma unroll
            for (int j = 0; j < 8; ++j) acc[j] += (float)v2_[j]; [[fallthrough]];
        case 2:
#pragma unroll
            for (int j = 0; j < 8; ++j) acc[j] += (float)v1_[j]; [[fallthrough]];
        case 1:
#pragma unroll
            for (int j = 0; j < 8; ++j) acc[j] += (float)v0_[j]; [[fallthrough]];
        default: break;
        }
    }

    // tail for deg > 6: clean branch-free 4-wide clusters (v1 pattern)
    int kk = 6;
    for (; kk + 3 < ns; kk += 4) {
        int n0 = sl[kk], n1 = sl[kk + 1];
        int n2 = sl[kk + 2], n3 = sl[kk + 3];
        if (active) {
            bf16x8 u0 = *(const bf16x8*)(Xbf + (size_t)n0 * GK + co);
            bf16x8 u1 = *(const bf16x8*)(Xbf + (size_t)n1 * GK + co);
            bf16x8 u2 = *(const bf16x8*)(Xbf + (size_t)n2 * GK + co);
            bf16x8 u3 = *(const bf16x8*)(Xbf + (size_t)n3 * GK + co);
#pragma unroll
            for (int j = 0; j < 8; ++j)
                acc[j] += ((float)u0[j] + (float)u1[j]) + ((float)u2[j] + (float)u3[j]);
        }
    }
    for (; kk < ns; ++kk) {
        int n0 = sl[kk];
        if (active) {
            bf16x8 v = *(const bf16x8*)(Xbf + (size_t)n0 * GK + co);
#pragma unroll
            for (int j = 0; j < 8; ++j) acc[j] += (float)v[j];
        }
    }

    if (cn > CAP) {                  // exact overflow path (rare/never)
        const int L = cnt[N_NODES];
        for (int i = 0; i < L; ++i) {
            if (ovf[2 * i] == node) {
                int n0 = ovf[2 * i + 1];
                if (active) {
                    bf16x8 v = *(const bf16x8*)(Xbf + (size_t)n0 * GK + co);
#pragma unroll
                    for (int j = 0; j < 8; ++j) acc[j] += (float)v[j];
                }
            }
        }
    }

    // fold fp32 noise via window-select (block-uniform d)
    if (active) {
        float nq[12];
        *(f32x4*)&nq[0] = na; *(f32x4*)&nq[4] = nb; *(f32x4*)&nq[8] = nc;
        if (t < 179) {
            switch (d) {
            case 0:
#pragma unroll
                for (int j = 0; j < 8; ++j) acc[j] += nq[0 + j];
                break;
            case 1:
#pragma unroll
                for (int j = 0; j < 8; ++j) acc[j] += nq[1 + j];
                break;
            case 2:
#pragma unroll
                for (int j = 0; j < 8; ++j) acc[j] += nq[2 + j];
                break;
            default:
#pragma unroll
                for (int j = 0; j < 8; ++j) acc[j] += nq[3 + j];
                break;
            }
        } else {                      // t == 179: only float col 1432 is real
            acc[0] += nq[8 + d];
        }
    }

    float ss = 0.f;
    if (active) {
        bf16x8 o;
#pragma unroll
        for (int j = 0; j < 8; ++j) { o[j] = (__bf16)acc[j]; ss += acc[j] * acc[j]; }
        *(bf16x8*)(aggbf + (size_t)node * GK + co) = o;
    }
    for (int off = 32; off > 0; off >>= 1) ss += __shfl_down(ss, off, 64);
    if ((t & 63) == 0) red[t >> 6] = ss;
    __syncthreads();
    if (t == 0)
        rnorm[node] = 1.0f / fmaxf(sqrtf(red[0] + red[1] + red[2]), 1e-12f);
}

// ---------------- bf16 MFMA GEMM: out = (aggbf @ WbfT^T) * rnorm + bias --------
// round-6 version (measured best; explicit dbuf regressed): BM=64, BN=64, BK=96
// -> 632 blocks (2.47/CU), 15 K-iterations. 4 waves in a 2x2 grid, each 32x32.
// XCD swizzle: 632 = 8*79 exactly -> the 4 col-siblings sharing a 64-row A
// panel land consecutively on one XCD -> A re-reads are L2 hits.

#define BKG 96
#define GEMM_NWG ((GM2 / 64) * (OUT_F / 64))   // 158*4 = 632

__global__ void __launch_bounds__(256) k_gemm(const __bf16* __restrict__ A,
                                              const __bf16* __restrict__ BT,
                                              const float* __restrict__ rnorm,
                                              const float* __restrict__ bias,
                                              float* __restrict__ out) {
    __shared__ __align__(16) __bf16 Asm[64][BKG];   // 12 KB
    __shared__ __align__(16) __bf16 Bsm[64][BKG];   // 12 KB

    const int t = threadIdx.x;
    const int lane = t & 63;
    const int w = t >> 6;
    const int wr = w >> 1, wc = w & 1;              // 2x2 wave grid

    const int L = blockIdx.x;                        // XCD-bijective swizzle
    const int xcd = L & 7, idx = L >> 3;
    const int work = xcd * (GEMM_NWG / 8) + idx;     // 632 % 8 == 0
    const int row0 = (work >> 2) * 64;
    const int col0 = (work & 3) * 64;

    f32x4 acc[2][2];
#pragma unroll
    for (int i = 0; i < 2; ++i)
#pragma unroll
        for (int j = 0; j < 2; ++j) acc[i][j] = (f32x4){0.f, 0.f, 0.f, 0.f};

    __bf16* asm0 = (__bf16*)Asm;
    __bf16* bsm0 = (__bf16*)Bsm;

    // staging: 64 rows x 12 granules(16B) = 768 granules each side; 3/thread
    auto stage_tile = [&](int k0) {
#pragma unroll
        for (int g2 = 0; g2 < 3; ++g2) {
            int g = t + g2 * 256;
            int r = g / 12, c16 = g % 12;
            stage16(A  + (size_t)(row0 + r) * GK + k0 + c16 * 8, asm0 + g * 8);
            stage16(BT + (size_t)(col0 + r) * GK + k0 + c16 * 8, bsm0 + g * 8);
        }
    };

    stage_tile(0);

    const int kq = (lane >> 4) * 8;
    const int l15 = lane & 15;

    for (int kt = 0; kt < GK / BKG; ++kt) {
        __syncthreads();

        bf16x8 af[2][3], bfr[2][3];
#pragma unroll
        for (int s = 0; s < 3; ++s) {
#pragma unroll
            for (int i = 0; i < 2; ++i) {
                af[i][s]  = *(const bf16x8*)&Asm[wr * 32 + i * 16 + l15][s * 32 + kq];
                bfr[i][s] = *(const bf16x8*)&Bsm[wc * 32 + i * 16 + l15][s * 32 + kq];
            }
        }

        __syncthreads();

        if (kt + 1 < GK / BKG) stage_tile((kt + 1) * BKG);

#pragma unroll
        for (int s = 0; s < 3; ++s)
#pragma unroll
            for (int i = 0; i < 2; ++i)
#pragma unroll
                for (int j = 0; j < 2; ++j)
                    acc[i][j] = __builtin_amdgcn_mfma_f32_16x16x32_bf16(af[i][s], bfr[j][s], acc[i][j], 0, 0, 0);
    }

    // epilogue: C/D layout col=lane&15, row=(lane>>4)*4+reg; fuse rnorm + bias
    const int rq4 = (lane >> 4) * 4;
#pragma unroll
    for (int i = 0; i < 2; ++i) {
        int gr0 = row0 + wr * 32 + i * 16 + rq4;
#pragma unroll
        for (int rr = 0; rr < 4; ++rr) {
            int gr = gr0 + rr;
            if (gr < N_NODES) {
                float rn = rnorm[gr];
#pragma unroll
                for (int j = 0; j < 2; ++j) {
                    int gc = col0 + wc * 32 + j * 16 + l15;
                    out[(size_t)gr * OUT_F + gc] = acc[i][j][rr] * rn + bias[gc];
                }
            }
        }
    }
}

// ---------------- launch ----------------

extern "C" void kernel_launch(void* const* d_in, const int* in_sizes, int n_in,
                              void* d_out, int out_size, void* d_ws, size_t ws_size,
                              hipStream_t stream) {
    const float* feat  = (const float*)d_in[0];
    const int*   edges = (const int*)d_in[1];
    const float* W     = (const float*)d_in[2];
    const float* bias  = (const float*)d_in[3];
    const float* noise = (const float*)d_in[4];
    float* out = (float*)d_out;

    char* ws = (char*)d_ws;
    size_t off = 0;
    auto carve = [&](size_t bytes) {
        void* p = ws + off;
        off = (off + bytes + 255) & ~(size_t)255;
        return p;
    };
    __bf16* Xbf     = (__bf16*)carve((size_t)N_NODES * GK * sizeof(__bf16));
    __bf16* aggbf   = (__bf16*)carve((size_t)GM2 * GK * sizeof(__bf16));
    __bf16* WbfT    = (__bf16*)carve((size_t)OUT_F * GK * sizeof(__bf16));
    float*  rnorm   = (float*)carve((size_t)N_NODES * sizeof(float));
    int*    cnt     = (int*)carve((size_t)(N_NODES + 1) * sizeof(int));   // +ovf count
    int*    slots   = (int*)carve((size_t)N_NODES * CAP * sizeof(int));
    int*    ovf     = (int*)carve((size_t)2 * N_EDGES * sizeof(int));
    (void)ws_size;

    hipMemsetAsync(cnt, 0, (size_t)(N_NODES + 1) * sizeof(int), stream);

    k_phaseA<<<PHASEA_BLKS, 256, 0, stream>>>(feat, Xbf, W, WbfT,
                                              edges, cnt, slots, ovf);

    k_agg<<<GM2, 192, 0, stream>>>(Xbf, noise, cnt, slots, ovf, aggbf, rnorm);

    k_gemm<<<GEMM_NWG, 256, 0, stream>>>(aggbf, WbfT, rnorm, bias, out);
}